// Round 8
// baseline (624.444 us; speedup 1.0000x reference)
//
#include <hip/hip_runtime.h>
#include <hip/hip_bf16.h>

#define N_NODES 50000
#define N_EDGES 800000
#define C_IN    128
#define C_H     64
#define C_HU    32                         // u32 words per bf16 row
#define N_LAYER 9
#define N_GRAPH 10
#define N_PER_G 5000
#define NSB     ((N_NODES + 255) / 256)    // 196 scan blocks
#define NPB     16                         // nodes per block in layer kernel

typedef unsigned int  u32;
typedef unsigned short u16;
typedef __bf16 bf16x8 __attribute__((ext_vector_type(8)));
typedef float  f32x4  __attribute__((ext_vector_type(4)));

__device__ __forceinline__ float bflo(u32 u) { return __uint_as_float(u << 16); }
__device__ __forceinline__ float bfhi(u32 u) { return __uint_as_float(u & 0xffff0000u); }
__device__ __forceinline__ u16 f2bf(float f) {            // RNE f32 -> bf16
    u32 u = __float_as_uint(f);
    u32 r = u + 0x7fffu + ((u >> 16) & 1u);
    return (u16)(r >> 16);
}
__device__ __forceinline__ void fma8(float* acc, uint4 v, float w) {
    acc[0] += bflo(v.x) * w; acc[1] += bfhi(v.x) * w;
    acc[2] += bflo(v.y) * w; acc[3] += bfhi(v.y) * w;
    acc[4] += bflo(v.z) * w; acc[5] += bfhi(v.z) * w;
    acc[6] += bflo(v.w) * w; acc[7] += bfhi(v.w) * w;
}

// ---------------- CSR build ----------------

__global__ void count_kernel(const int* __restrict__ dst, int* __restrict__ cnt, int e) {
    int i = blockIdx.x * blockDim.x + threadIdx.x;
    if (i < e) atomicAdd(&cnt[dst[i]], 1);
}

__global__ __launch_bounds__(256) void bsum_kernel(const int* __restrict__ cnt,
                                                   int* __restrict__ bsum) {
    int i = blockIdx.x * 256 + threadIdx.x;
    int v = (i < N_NODES) ? cnt[i] : 0;
#pragma unroll
    for (int off = 32; off; off >>= 1) v += __shfl_down(v, off);
    __shared__ int s[4];
    if ((threadIdx.x & 63) == 0) s[threadIdx.x >> 6] = v;
    __syncthreads();
    if (threadIdx.x == 0) bsum[blockIdx.x] = s[0] + s[1] + s[2] + s[3];
}

__global__ __launch_bounds__(256) void scan2_kernel(const int* __restrict__ cnt,
                                                    const int* __restrict__ bsum,
                                                    int* __restrict__ rowStart,
                                                    int* __restrict__ cursor,
                                                    float* __restrict__ dinv) {
    int b = blockIdx.x, t = threadIdx.x;
    int v = (t < b) ? bsum[t] : 0;
#pragma unroll
    for (int off = 32; off; off >>= 1) v += __shfl_down(v, off);
    __shared__ int sw[4];
    __shared__ int soff;
    if ((t & 63) == 0) sw[t >> 6] = v;
    __syncthreads();
    if (t == 0) soff = sw[0] + sw[1] + sw[2] + sw[3];

    int i = b * 256 + t;
    int c = (i < N_NODES) ? cnt[i] : 0;
    __shared__ int sd[256];
    sd[t] = c;
    __syncthreads();
#pragma unroll
    for (int off = 1; off < 256; off <<= 1) {
        int x = sd[t];
        int y = (t >= off) ? sd[t - off] : 0;
        __syncthreads();
        sd[t] = x + y;
        __syncthreads();
    }
    if (i < N_NODES) {
        int rs = soff + sd[t] - c;
        rowStart[i] = rs;
        cursor[i] = rs;
        dinv[i] = rsqrtf((float)c + 1.0f);
    }
}

__global__ void scatter_kernel(const int* __restrict__ src, const int* __restrict__ dst,
                               int* __restrict__ cursor, const float* __restrict__ dinv,
                               int2* __restrict__ csr_sw, int e) {
    int i = blockIdx.x * blockDim.x + threadIdx.x;
    if (i < e) {
        int d = dst[i], s = src[i];
        int p = atomicAdd(&cursor[d], 1);
        float w = dinv[s] * dinv[d];
        csr_sw[p] = make_int2(s, __float_as_int(w));
    }
}

// ---------------- layer 0 input GEMM via MFMA: hw0 = x @ W0 (K=128), bf16 out ----------------

__global__ __launch_bounds__(256, 4) void gemm0_kernel(const float* __restrict__ x,
                                                       const float* __restrict__ W0,
                                                       u16* __restrict__ out) {
    __shared__ float Wlds[C_IN * C_H];   // 32 KB fp32
    for (int t = threadIdx.x; t < (C_IN * C_H) / 4; t += 256)
        *(float4*)&Wlds[t * 4] = *(const float4*)&W0[t * 4];
    __syncthreads();

    int wid = threadIdx.x >> 6, lane = threadIdx.x & 63;
    int lr = lane & 15, lg = lane >> 4;

    bf16x8 bfr[4][4];   // [col-tile][k-step]
#pragma unroll
    for (int ct = 0; ct < 4; ct++)
#pragma unroll
        for (int kk = 0; kk < 4; kk++)
#pragma unroll
            for (int j = 0; j < 8; j++)
                bfr[ct][kk][j] = (__bf16)Wlds[(kk * 32 + lg * 8 + j) * C_H + ct * 16 + lr];

    for (int t = blockIdx.x * 4 + wid; t < N_NODES / 16; t += gridDim.x * 4) {
        int row0 = t * 16;
        bf16x8 af[4];
#pragma unroll
        for (int kk = 0; kk < 4; kk++) {
            const float* xp = x + (size_t)(row0 + lr) * C_IN + kk * 32 + lg * 8;
            float4 p0 = *(const float4*)xp;
            float4 p1 = *(const float4*)(xp + 4);
            af[kk][0] = (__bf16)p0.x; af[kk][1] = (__bf16)p0.y;
            af[kk][2] = (__bf16)p0.z; af[kk][3] = (__bf16)p0.w;
            af[kk][4] = (__bf16)p1.x; af[kk][5] = (__bf16)p1.y;
            af[kk][6] = (__bf16)p1.z; af[kk][7] = (__bf16)p1.w;
        }
        f32x4 acc[4];
#pragma unroll
        for (int ct = 0; ct < 4; ct++) acc[ct] = (f32x4){0.f, 0.f, 0.f, 0.f};
#pragma unroll
        for (int ct = 0; ct < 4; ct++)
#pragma unroll
            for (int kk = 0; kk < 4; kk++)
                acc[ct] = __builtin_amdgcn_mfma_f32_16x16x32_bf16(af[kk], bfr[ct][kk], acc[ct], 0, 0, 0);
#pragma unroll
        for (int ct = 0; ct < 4; ct++)
#pragma unroll
            for (int reg = 0; reg < 4; reg++) {
                int rr = row0 + lg * 4 + reg;
                out[(size_t)rr * C_H + ct * 16 + lr] = f2bf(acc[ct][reg]);
            }
    }
}

// ---------------- fused layer: 4 CONSECUTIVE nodes per wave, concurrent gather ----------------
// 8 edge-groups x 8 lanes (lane = 8 bf16 channels, one uint4/edge); 4 nodes x
// 2-deep unroll => 8 independent row loads in flight per wave.

#define GLOAD(n, sq, dq)                                                          \
    int ia##n = (ea < dq) ? ea : 0, ib##n = (eb < dq) ? eb : 0;                   \
    int2 ca##n = csr_sw[sq + ia##n]; int2 cb##n = csr_sw[sq + ib##n];             \
    int ra##n = (ea < dq) ? ca##n.x : 0;                                          \
    int rb##n = (eb < dq) ? cb##n.x : 0;                                          \
    uint4 va##n = *(const uint4*)(hw + (size_t)ra##n * C_HU + r * 4);             \
    uint4 vb##n = *(const uint4*)(hw + (size_t)rb##n * C_HU + r * 4);             \
    float wa##n = (ea < dq) ? __int_as_float(ca##n.y) : 0.f;                      \
    float wb##n = (eb < dq) ? __int_as_float(cb##n.y) : 0.f;

#define GFMA(n, Aq) fma8(Aq, va##n, wa##n); fma8(Aq, vb##n, wb##n);

#define RED(Aq)                                                                   \
    _Pragma("unroll")                                                             \
    for (int c = 0; c < 8; c++) {                                                 \
        Aq[c] += __shfl_xor(Aq[c], 8);                                            \
        Aq[c] += __shfl_xor(Aq[c], 16);                                           \
        Aq[c] += __shfl_xor(Aq[c], 32);                                           \
    }

#define EPILOG(q, iq, Aq)                                                         \
    {                                                                             \
        float di = dinv[iq]; float sl = di * di;                                  \
        uint4 sv = *(const uint4*)(hw + (size_t)(iq) * C_HU + r * 4);             \
        if (g == 0) {                                                             \
            float4 hA, hB;                                                        \
            hA.x = fmaxf(Aq[0] + bflo(sv.x) * sl + b8[0], 0.f);                   \
            hA.y = fmaxf(Aq[1] + bfhi(sv.x) * sl + b8[1], 0.f);                   \
            hA.z = fmaxf(Aq[2] + bflo(sv.y) * sl + b8[2], 0.f);                   \
            hA.w = fmaxf(Aq[3] + bfhi(sv.y) * sl + b8[3], 0.f);                   \
            hB.x = fmaxf(Aq[4] + bflo(sv.z) * sl + b8[4], 0.f);                   \
            hB.y = fmaxf(Aq[5] + bfhi(sv.z) * sl + b8[5], 0.f);                   \
            hB.z = fmaxf(Aq[6] + bflo(sv.w) * sl + b8[6], 0.f);                   \
            hB.w = fmaxf(Aq[7] + bfhi(sv.w) * sl + b8[7], 0.f);                   \
            *(float4*)&hbuf[wave * 4 + q][r * 8] = hA;                            \
            *(float4*)&hbuf[wave * 4 + q][r * 8 + 4] = hB;                        \
        }                                                                         \
    }

#define GEMV(q, iq)                                                               \
    {                                                                             \
        float o0 = 0.f, o1 = 0.f;                                                 \
        _Pragma("unroll")                                                         \
        for (int k4 = 0; k4 < C_H / 4; k4++) {                                    \
            float4 hk = *(const float4*)&hbuf[wave * 4 + q][k4 * 4];              \
            o0 += hk.x * Wlds[(k4 * 4 + 0) * C_H + lane];                         \
            o1 += hk.y * Wlds[(k4 * 4 + 1) * C_H + lane];                         \
            o0 += hk.z * Wlds[(k4 * 4 + 2) * C_H + lane];                         \
            o1 += hk.w * Wlds[(k4 * 4 + 3) * C_H + lane];                         \
        }                                                                         \
        out[(size_t)(iq) * C_H + lane] = f2bf(o0 + o1);                           \
    }

__global__ __launch_bounds__(256, 4) void layer_kernel(const u32* __restrict__ hw,
                                                       const int* __restrict__ rowStart,
                                                       const int* __restrict__ cnt,
                                                       const int2* __restrict__ csr_sw,
                                                       const float* __restrict__ dinv,
                                                       const float* __restrict__ bias,
                                                       const float* __restrict__ Wnext,
                                                       u16* __restrict__ out) {
    __shared__ float Wlds[C_H * C_H];   // 16 KB
    __shared__ float hbuf[NPB][C_H];    // 4 KB
    for (int t = threadIdx.x; t < (C_H * C_H) / 4; t += 256)
        *(float4*)&Wlds[t * 4] = *(const float4*)&Wnext[t * 4];

    int wave = threadIdx.x >> 6, lane = threadIdx.x & 63;
    int g = lane >> 3;          // edge sub-group 0..7
    int r = lane & 7;           // channel chunk: channels 8r..8r+7
    int jbase = blockIdx.x * NPB + wave * 4;

    int i0 = jbase + 0, i1 = jbase + 1, i2 = jbase + 2, i3 = jbase + 3;
    int s0 = rowStart[i0], s1 = rowStart[i1], s2 = rowStart[i2], s3 = rowStart[i3];
    int d0 = cnt[i0], d1 = cnt[i1], d2 = cnt[i2], d3 = cnt[i3];
    int dmax = max(max(d0, d1), max(d2, d3));

    float b8[8];
    *(float4*)&b8[0] = *(const float4*)(bias + r * 8);
    *(float4*)&b8[4] = *(const float4*)(bias + r * 8 + 4);

    float A0[8] = {0.f,0.f,0.f,0.f,0.f,0.f,0.f,0.f};
    float A1[8] = {0.f,0.f,0.f,0.f,0.f,0.f,0.f,0.f};
    float A2[8] = {0.f,0.f,0.f,0.f,0.f,0.f,0.f,0.f};
    float A3[8] = {0.f,0.f,0.f,0.f,0.f,0.f,0.f,0.f};

    for (int base = 0; base < dmax; base += 16) {
        int ea = base + g, eb = ea + 8;
        GLOAD(0, s0, d0)
        GLOAD(1, s1, d1)
        GLOAD(2, s2, d2)
        GLOAD(3, s3, d3)
        GFMA(0, A0)
        GFMA(1, A1)
        GFMA(2, A2)
        GFMA(3, A3)
    }

    RED(A0) RED(A1) RED(A2) RED(A3)

    EPILOG(0, i0, A0)
    EPILOG(1, i1, A1)
    EPILOG(2, i2, A2)
    EPILOG(3, i3, A3)

    __syncthreads();   // Wlds fill + hbuf visibility

    GEMV(0, i0)
    GEMV(1, i1)
    GEMV(2, i2)
    GEMV(3, i3)
}

// ---------------- pooling head ----------------

__global__ __launch_bounds__(256) void pool_kernel(const u16* __restrict__ hn,
                                                   float* __restrict__ poolbuf) {
    int g = blockIdx.x >> 4;
    int s = blockIdx.x & 15;
    int lane = threadIdx.x & 63;
    int rg = threadIdx.x >> 6;
    int stream = s * 4 + rg;
    float acc = 0.f;
    for (int r = stream; r < N_PER_G; r += 64)
        acc += bflo((u32)hn[(size_t)(g * N_PER_G + r) * C_H + lane]);
    __shared__ float red[4][C_H];
    red[rg][lane] = acc;
    __syncthreads();
    if (rg == 0) {
        float t = red[0][lane] + red[1][lane] + red[2][lane] + red[3][lane];
        atomicAdd(&poolbuf[g * C_H + lane], t);
    }
}

__global__ void poolwp_kernel(const float* __restrict__ poolbuf,
                              const float* __restrict__ Wp,
                              float* __restrict__ poolwp) {
    int g = blockIdx.x, c = threadIdx.x;
    float o = 0.f;
#pragma unroll 8
    for (int k = 0; k < C_H; k++) o += poolbuf[g * C_H + k] * Wp[k * C_H + c];
    poolwp[g * C_H + c] = o;
}

__global__ __launch_bounds__(256) void final_kernel(const u16* __restrict__ hn,
                                                    const float* __restrict__ poolwp,
                                                    const float* __restrict__ Wa,
                                                    float* __restrict__ out, int n) {
    int wave = threadIdx.x >> 6, lane = threadIdx.x & 63;
    int i = blockIdx.x * 4 + wave;
    if (i >= n) return;
    int g = i / N_PER_G;
    float v = fmaxf(bflo((u32)hn[(size_t)i * C_H + lane]), 0.f) * Wa[lane]
            + fmaxf(poolwp[g * C_H + lane], 0.f) * Wa[C_H + lane];
#pragma unroll
    for (int off = 32; off; off >>= 1) v += __shfl_down(v, off);
    if (lane == 0) out[i] = tanhf(v);
}

// ---------------- launch ----------------

extern "C" void kernel_launch(void* const* d_in, const int* in_sizes, int n_in,
                              void* d_out, int out_size, void* d_ws, size_t ws_size,
                              hipStream_t stream) {
    const float* x   = (const float*)d_in[0];
    const int*   ei  = (const int*)d_in[1];
    const float* W0  = (const float*)d_in[2];
    const float* b0  = (const float*)d_in[3];
    const float* Ws  = (const float*)d_in[4];
    const float* bs  = (const float*)d_in[5];
    const float* Wn  = (const float*)d_in[6];
    const float* Wp  = (const float*)d_in[7];
    const float* Wa  = (const float*)d_in[8];
    float* out = (float*)d_out;

    const int* e_src = ei;
    const int* e_dst = ei + N_EDGES;

    size_t off = 0;
    auto alloc = [&](size_t bytes) { size_t o = off; off = (off + bytes + 255) & ~(size_t)255; return o; };
    char* ws = (char*)d_ws;
    int*   cnt      = (int*)  (ws + alloc(N_NODES * 4));
    int*   rowStart = (int*)  (ws + alloc(N_NODES * 4));
    int*   cursor   = (int*)  (ws + alloc(N_NODES * 4));
    float* dinv     = (float*)(ws + alloc(N_NODES * 4));
    int*   bsum     = (int*)  (ws + alloc(NSB * 4));
    int2*  csr_sw   = (int2*) (ws + alloc((size_t)N_EDGES * 8));
    u16*   bufA     = (u16*)  (ws + alloc((size_t)N_NODES * C_H * 2));
    u16*   bufB     = (u16*)  (ws + alloc((size_t)N_NODES * C_H * 2));
    float* poolbuf  = (float*)(ws + alloc(N_GRAPH * C_H * 4));
    float* poolwp   = (float*)(ws + alloc(N_GRAPH * C_H * 4));

    hipMemsetAsync(cnt, 0, N_NODES * 4, stream);
    hipMemsetAsync(poolbuf, 0, N_GRAPH * C_H * 4, stream);

    const int EB = (N_EDGES + 255) / 256;
    count_kernel<<<EB, 256, 0, stream>>>(e_dst, cnt, N_EDGES);
    bsum_kernel<<<NSB, 256, 0, stream>>>(cnt, bsum);
    scan2_kernel<<<NSB, 256, 0, stream>>>(cnt, bsum, rowStart, cursor, dinv);
    scatter_kernel<<<EB, 256, 0, stream>>>(e_src, e_dst, cursor, dinv, csr_sw, N_EDGES);

    gemm0_kernel<<<782, 256, 0, stream>>>(x, W0, bufA);

    const int LB = N_NODES / NPB;   // 3125
    for (int k = 0; k < N_LAYER; k++) {
        const u16* hin  = (k & 1) ? bufB : bufA;
        u16*       hout = (k & 1) ? bufA : bufB;
        const float* bias  = (k == 0) ? b0 : (bs + (k - 1) * C_H);
        const float* Wnext = (k < N_LAYER - 1) ? (Ws + k * C_H * C_H) : Wn;
        layer_kernel<<<LB, 256, 0, stream>>>((const u32*)hin, rowStart, cnt, csr_sw,
                                             dinv, bias, Wnext, hout);
    }
    const u16* hn = bufB;   // layer 8 output

    pool_kernel<<<N_GRAPH * 16, 256, 0, stream>>>(hn, poolbuf);
    poolwp_kernel<<<N_GRAPH, C_H, 0, stream>>>(poolbuf, Wp, poolwp);
    final_kernel<<<N_NODES / 4, 256, 0, stream>>>(hn, poolwp, Wa, out, N_NODES);
}

// Round 9
// 578.099 us; speedup vs baseline: 1.0802x; 1.0802x over previous
//
#include <hip/hip_runtime.h>
#include <hip/hip_bf16.h>

#define N_NODES 50000
#define N_EDGES 800000
#define C_IN    128
#define C_H     64
#define C_HU    32                         // u32 words per bf16 row
#define N_LAYER 9
#define N_GRAPH 10
#define N_PER_G 5000
#define NSB     ((N_NODES + 255) / 256)    // 196 scan blocks
#define NPB     16                         // nodes per block in layer kernel

typedef unsigned int  u32;
typedef unsigned short u16;
typedef __bf16 bf16x8 __attribute__((ext_vector_type(8)));
typedef float  f32x4  __attribute__((ext_vector_type(4)));

__device__ __forceinline__ float bflo(u32 u) { return __uint_as_float(u << 16); }
__device__ __forceinline__ float bfhi(u32 u) { return __uint_as_float(u & 0xffff0000u); }
__device__ __forceinline__ u16 f2bf(float f) {            // RNE f32 -> bf16
    u32 u = __float_as_uint(f);
    u32 r = u + 0x7fffu + ((u >> 16) & 1u);
    return (u16)(r >> 16);
}
__device__ __forceinline__ void fma8(float* acc, uint4 v, float w) {
    acc[0] += bflo(v.x) * w; acc[1] += bfhi(v.x) * w;
    acc[2] += bflo(v.y) * w; acc[3] += bfhi(v.y) * w;
    acc[4] += bflo(v.z) * w; acc[5] += bfhi(v.z) * w;
    acc[6] += bflo(v.w) * w; acc[7] += bfhi(v.w) * w;
}

// ---------------- CSR build ----------------

__global__ void count_kernel(const int* __restrict__ dst, int* __restrict__ cnt, int e) {
    int i = blockIdx.x * blockDim.x + threadIdx.x;
    if (i < e) atomicAdd(&cnt[dst[i]], 1);
}

__global__ __launch_bounds__(256) void bsum_kernel(const int* __restrict__ cnt,
                                                   int* __restrict__ bsum) {
    int i = blockIdx.x * 256 + threadIdx.x;
    int v = (i < N_NODES) ? cnt[i] : 0;
#pragma unroll
    for (int off = 32; off; off >>= 1) v += __shfl_down(v, off);
    __shared__ int s[4];
    if ((threadIdx.x & 63) == 0) s[threadIdx.x >> 6] = v;
    __syncthreads();
    if (threadIdx.x == 0) bsum[blockIdx.x] = s[0] + s[1] + s[2] + s[3];
}

__global__ __launch_bounds__(256) void scan2_kernel(const int* __restrict__ cnt,
                                                    const int* __restrict__ bsum,
                                                    int* __restrict__ rowStart,
                                                    int* __restrict__ cursor,
                                                    float* __restrict__ dinv) {
    int b = blockIdx.x, t = threadIdx.x;
    int v = (t < b) ? bsum[t] : 0;
#pragma unroll
    for (int off = 32; off; off >>= 1) v += __shfl_down(v, off);
    __shared__ int sw[4];
    __shared__ int soff;
    if ((t & 63) == 0) sw[t >> 6] = v;
    __syncthreads();
    if (t == 0) soff = sw[0] + sw[1] + sw[2] + sw[3];

    int i = b * 256 + t;
    int c = (i < N_NODES) ? cnt[i] : 0;
    __shared__ int sd[256];
    sd[t] = c;
    __syncthreads();
#pragma unroll
    for (int off = 1; off < 256; off <<= 1) {
        int x = sd[t];
        int y = (t >= off) ? sd[t - off] : 0;
        __syncthreads();
        sd[t] = x + y;
        __syncthreads();
    }
    if (i < N_NODES) {
        int rs = soff + sd[t] - c;
        rowStart[i] = rs;
        cursor[i] = rs;
        dinv[i] = rsqrtf((float)c + 1.0f);
    }
}

__global__ void scatter_kernel(const int* __restrict__ src, const int* __restrict__ dst,
                               int* __restrict__ cursor, const float* __restrict__ dinv,
                               int2* __restrict__ csr_sw, int e) {
    int i = blockIdx.x * blockDim.x + threadIdx.x;
    if (i < e) {
        int d = dst[i], s = src[i];
        int p = atomicAdd(&cursor[d], 1);
        float w = dinv[s] * dinv[d];
        csr_sw[p] = make_int2(s, __float_as_int(w));
    }
}

// ---------------- layer 0 input GEMM via MFMA: hw0 = x @ W0 (K=128), bf16 out ----------------
// No VGPR cap (prev (256,4) caused accumulator spill-to-scratch). 2 tiles/wave.

__global__ __launch_bounds__(256) void gemm0_kernel(const float* __restrict__ x,
                                                    const float* __restrict__ W0,
                                                    u16* __restrict__ out) {
    __shared__ float Wlds[C_IN * C_H];   // 32 KB fp32
    for (int t = threadIdx.x; t < (C_IN * C_H) / 4; t += 256)
        *(float4*)&Wlds[t * 4] = *(const float4*)&W0[t * 4];
    __syncthreads();

    int wid = threadIdx.x >> 6, lane = threadIdx.x & 63;
    int lr = lane & 15, lg = lane >> 4;

    bf16x8 bfr[4][4];   // [col-tile][k-step]
#pragma unroll
    for (int ct = 0; ct < 4; ct++)
#pragma unroll
        for (int kk = 0; kk < 4; kk++)
#pragma unroll
            for (int j = 0; j < 8; j++)
                bfr[ct][kk][j] = (__bf16)Wlds[(kk * 32 + lg * 8 + j) * C_H + ct * 16 + lr];

    for (int t = blockIdx.x * 4 + wid; t < N_NODES / 16; t += gridDim.x * 4) {
        int row0 = t * 16;
        bf16x8 af[4];
#pragma unroll
        for (int kk = 0; kk < 4; kk++) {
            const float* xp = x + (size_t)(row0 + lr) * C_IN + kk * 32 + lg * 8;
            float4 p0 = *(const float4*)xp;
            float4 p1 = *(const float4*)(xp + 4);
            af[kk][0] = (__bf16)p0.x; af[kk][1] = (__bf16)p0.y;
            af[kk][2] = (__bf16)p0.z; af[kk][3] = (__bf16)p0.w;
            af[kk][4] = (__bf16)p1.x; af[kk][5] = (__bf16)p1.y;
            af[kk][6] = (__bf16)p1.z; af[kk][7] = (__bf16)p1.w;
        }
        f32x4 acc[4];
#pragma unroll
        for (int ct = 0; ct < 4; ct++) acc[ct] = (f32x4){0.f, 0.f, 0.f, 0.f};
#pragma unroll
        for (int ct = 0; ct < 4; ct++)
#pragma unroll
            for (int kk = 0; kk < 4; kk++)
                acc[ct] = __builtin_amdgcn_mfma_f32_16x16x32_bf16(af[kk], bfr[ct][kk], acc[ct], 0, 0, 0);
#pragma unroll
        for (int ct = 0; ct < 4; ct++)
#pragma unroll
            for (int reg = 0; reg < 4; reg++) {
                int rr = row0 + lg * 4 + reg;
                out[(size_t)rr * C_H + ct * 16 + lr] = f2bf(acc[ct][reg]);
            }
    }
}

// ---------------- fused layer: 4 CONSECUTIVE nodes per wave, concurrent gather ----------------
// 8 edge-groups x 8 lanes (lane = 8 bf16 channels, one uint4/edge); 4 nodes x
// 2-deep unroll => 8 independent row loads in flight per wave.
// NOTE: plain __launch_bounds__(256) — the (256,4) cap made the compiler spill
// all 4 accumulator sets to scratch (VGPR=64, WRITE_SIZE 9x output).

#define GLOAD(n, sq, dq)                                                          \
    int ia##n = (ea < dq) ? ea : 0, ib##n = (eb < dq) ? eb : 0;                   \
    int2 ca##n = csr_sw[sq + ia##n]; int2 cb##n = csr_sw[sq + ib##n];             \
    int ra##n = (ea < dq) ? ca##n.x : 0;                                          \
    int rb##n = (eb < dq) ? cb##n.x : 0;                                          \
    uint4 va##n = *(const uint4*)(hw + (size_t)ra##n * C_HU + r * 4);             \
    uint4 vb##n = *(const uint4*)(hw + (size_t)rb##n * C_HU + r * 4);             \
    float wa##n = (ea < dq) ? __int_as_float(ca##n.y) : 0.f;                      \
    float wb##n = (eb < dq) ? __int_as_float(cb##n.y) : 0.f;

#define GFMA(n, Aq) fma8(Aq, va##n, wa##n); fma8(Aq, vb##n, wb##n);

#define RED(Aq)                                                                   \
    _Pragma("unroll")                                                             \
    for (int c = 0; c < 8; c++) {                                                 \
        Aq[c] += __shfl_xor(Aq[c], 8);                                            \
        Aq[c] += __shfl_xor(Aq[c], 16);                                           \
        Aq[c] += __shfl_xor(Aq[c], 32);                                           \
    }

#define EPILOG(q, iq, Aq)                                                         \
    {                                                                             \
        float di = dinv[iq]; float sl = di * di;                                  \
        uint4 sv = *(const uint4*)(hw + (size_t)(iq) * C_HU + r * 4);             \
        if (g == 0) {                                                             \
            float4 hA, hB;                                                        \
            hA.x = fmaxf(Aq[0] + bflo(sv.x) * sl + b8[0], 0.f);                   \
            hA.y = fmaxf(Aq[1] + bfhi(sv.x) * sl + b8[1], 0.f);                   \
            hA.z = fmaxf(Aq[2] + bflo(sv.y) * sl + b8[2], 0.f);                   \
            hA.w = fmaxf(Aq[3] + bfhi(sv.y) * sl + b8[3], 0.f);                   \
            hB.x = fmaxf(Aq[4] + bflo(sv.z) * sl + b8[4], 0.f);                   \
            hB.y = fmaxf(Aq[5] + bfhi(sv.z) * sl + b8[5], 0.f);                   \
            hB.z = fmaxf(Aq[6] + bflo(sv.w) * sl + b8[6], 0.f);                   \
            hB.w = fmaxf(Aq[7] + bfhi(sv.w) * sl + b8[7], 0.f);                   \
            *(float4*)&hbuf[wave * 4 + q][r * 8] = hA;                            \
            *(float4*)&hbuf[wave * 4 + q][r * 8 + 4] = hB;                        \
        }                                                                         \
    }

#define GEMV(q, iq)                                                               \
    {                                                                             \
        float o0 = 0.f, o1 = 0.f;                                                 \
        _Pragma("unroll")                                                         \
        for (int k4 = 0; k4 < C_H / 4; k4++) {                                    \
            float4 hk = *(const float4*)&hbuf[wave * 4 + q][k4 * 4];              \
            o0 += hk.x * Wlds[(k4 * 4 + 0) * C_H + lane];                         \
            o1 += hk.y * Wlds[(k4 * 4 + 1) * C_H + lane];                         \
            o0 += hk.z * Wlds[(k4 * 4 + 2) * C_H + lane];                         \
            o1 += hk.w * Wlds[(k4 * 4 + 3) * C_H + lane];                         \
        }                                                                         \
        out[(size_t)(iq) * C_H + lane] = f2bf(o0 + o1);                           \
    }

__global__ __launch_bounds__(256) void layer_kernel(const u32* __restrict__ hw,
                                                    const int* __restrict__ rowStart,
                                                    const int* __restrict__ cnt,
                                                    const int2* __restrict__ csr_sw,
                                                    const float* __restrict__ dinv,
                                                    const float* __restrict__ bias,
                                                    const float* __restrict__ Wnext,
                                                    u16* __restrict__ out) {
    __shared__ float Wlds[C_H * C_H];   // 16 KB
    __shared__ float hbuf[NPB][C_H];    // 4 KB
    for (int t = threadIdx.x; t < (C_H * C_H) / 4; t += 256)
        *(float4*)&Wlds[t * 4] = *(const float4*)&Wnext[t * 4];

    int wave = threadIdx.x >> 6, lane = threadIdx.x & 63;
    int g = lane >> 3;          // edge sub-group 0..7
    int r = lane & 7;           // channel chunk: channels 8r..8r+7
    int jbase = blockIdx.x * NPB + wave * 4;

    int i0 = jbase + 0, i1 = jbase + 1, i2 = jbase + 2, i3 = jbase + 3;
    int s0 = rowStart[i0], s1 = rowStart[i1], s2 = rowStart[i2], s3 = rowStart[i3];
    int d0 = cnt[i0], d1 = cnt[i1], d2 = cnt[i2], d3 = cnt[i3];
    int dmax = max(max(d0, d1), max(d2, d3));

    float b8[8];
    *(float4*)&b8[0] = *(const float4*)(bias + r * 8);
    *(float4*)&b8[4] = *(const float4*)(bias + r * 8 + 4);

    float A0[8] = {0.f,0.f,0.f,0.f,0.f,0.f,0.f,0.f};
    float A1[8] = {0.f,0.f,0.f,0.f,0.f,0.f,0.f,0.f};
    float A2[8] = {0.f,0.f,0.f,0.f,0.f,0.f,0.f,0.f};
    float A3[8] = {0.f,0.f,0.f,0.f,0.f,0.f,0.f,0.f};

    for (int base = 0; base < dmax; base += 16) {
        int ea = base + g, eb = ea + 8;
        GLOAD(0, s0, d0)
        GLOAD(1, s1, d1)
        GLOAD(2, s2, d2)
        GLOAD(3, s3, d3)
        GFMA(0, A0)
        GFMA(1, A1)
        GFMA(2, A2)
        GFMA(3, A3)
    }

    RED(A0) RED(A1) RED(A2) RED(A3)

    EPILOG(0, i0, A0)
    EPILOG(1, i1, A1)
    EPILOG(2, i2, A2)
    EPILOG(3, i3, A3)

    __syncthreads();   // Wlds fill + hbuf visibility

    GEMV(0, i0)
    GEMV(1, i1)
    GEMV(2, i2)
    GEMV(3, i3)
}

// ---------------- pooling head ----------------

__global__ __launch_bounds__(256) void pool_kernel(const u16* __restrict__ hn,
                                                   float* __restrict__ poolbuf) {
    int g = blockIdx.x >> 4;
    int s = blockIdx.x & 15;
    int lane = threadIdx.x & 63;
    int rg = threadIdx.x >> 6;
    int stream = s * 4 + rg;
    float acc = 0.f;
    for (int r = stream; r < N_PER_G; r += 64)
        acc += bflo((u32)hn[(size_t)(g * N_PER_G + r) * C_H + lane]);
    __shared__ float red[4][C_H];
    red[rg][lane] = acc;
    __syncthreads();
    if (rg == 0) {
        float t = red[0][lane] + red[1][lane] + red[2][lane] + red[3][lane];
        atomicAdd(&poolbuf[g * C_H + lane], t);
    }
}

__global__ void poolwp_kernel(const float* __restrict__ poolbuf,
                              const float* __restrict__ Wp,
                              float* __restrict__ poolwp) {
    int g = blockIdx.x, c = threadIdx.x;
    float o = 0.f;
#pragma unroll 8
    for (int k = 0; k < C_H; k++) o += poolbuf[g * C_H + k] * Wp[k * C_H + c];
    poolwp[g * C_H + c] = o;
}

__global__ __launch_bounds__(256) void final_kernel(const u16* __restrict__ hn,
                                                    const float* __restrict__ poolwp,
                                                    const float* __restrict__ Wa,
                                                    float* __restrict__ out, int n) {
    int wave = threadIdx.x >> 6, lane = threadIdx.x & 63;
    int i = blockIdx.x * 4 + wave;
    if (i >= n) return;
    int g = i / N_PER_G;
    float v = fmaxf(bflo((u32)hn[(size_t)i * C_H + lane]), 0.f) * Wa[lane]
            + fmaxf(poolwp[g * C_H + lane], 0.f) * Wa[C_H + lane];
#pragma unroll
    for (int off = 32; off; off >>= 1) v += __shfl_down(v, off);
    if (lane == 0) out[i] = tanhf(v);
}

// ---------------- launch ----------------

extern "C" void kernel_launch(void* const* d_in, const int* in_sizes, int n_in,
                              void* d_out, int out_size, void* d_ws, size_t ws_size,
                              hipStream_t stream) {
    const float* x   = (const float*)d_in[0];
    const int*   ei  = (const int*)d_in[1];
    const float* W0  = (const float*)d_in[2];
    const float* b0  = (const float*)d_in[3];
    const float* Ws  = (const float*)d_in[4];
    const float* bs  = (const float*)d_in[5];
    const float* Wn  = (const float*)d_in[6];
    const float* Wp  = (const float*)d_in[7];
    const float* Wa  = (const float*)d_in[8];
    float* out = (float*)d_out;

    const int* e_src = ei;
    const int* e_dst = ei + N_EDGES;

    size_t off = 0;
    auto alloc = [&](size_t bytes) { size_t o = off; off = (off + bytes + 255) & ~(size_t)255; return o; };
    char* ws = (char*)d_ws;
    int*   cnt      = (int*)  (ws + alloc(N_NODES * 4));
    int*   rowStart = (int*)  (ws + alloc(N_NODES * 4));
    int*   cursor   = (int*)  (ws + alloc(N_NODES * 4));
    float* dinv     = (float*)(ws + alloc(N_NODES * 4));
    int*   bsum     = (int*)  (ws + alloc(NSB * 4));
    int2*  csr_sw   = (int2*) (ws + alloc((size_t)N_EDGES * 8));
    u16*   bufA     = (u16*)  (ws + alloc((size_t)N_NODES * C_H * 2));
    u16*   bufB     = (u16*)  (ws + alloc((size_t)N_NODES * C_H * 2));
    float* poolbuf  = (float*)(ws + alloc(N_GRAPH * C_H * 4));
    float* poolwp   = (float*)(ws + alloc(N_GRAPH * C_H * 4));

    hipMemsetAsync(cnt, 0, N_NODES * 4, stream);
    hipMemsetAsync(poolbuf, 0, N_GRAPH * C_H * 4, stream);

    const int EB = (N_EDGES + 255) / 256;
    count_kernel<<<EB, 256, 0, stream>>>(e_dst, cnt, N_EDGES);
    bsum_kernel<<<NSB, 256, 0, stream>>>(cnt, bsum);
    scan2_kernel<<<NSB, 256, 0, stream>>>(cnt, bsum, rowStart, cursor, dinv);
    scatter_kernel<<<EB, 256, 0, stream>>>(e_src, e_dst, cursor, dinv, csr_sw, N_EDGES);

    gemm0_kernel<<<391, 256, 0, stream>>>(x, W0, bufA);   // 2 tiles/wave

    const int LB = N_NODES / NPB;   // 3125
    for (int k = 0; k < N_LAYER; k++) {
        const u16* hin  = (k & 1) ? bufB : bufA;
        u16*       hout = (k & 1) ? bufA : bufB;
        const float* bias  = (k == 0) ? b0 : (bs + (k - 1) * C_H);
        const float* Wnext = (k < N_LAYER - 1) ? (Ws + k * C_H * C_H) : Wn;
        layer_kernel<<<LB, 256, 0, stream>>>((const u32*)hin, rowStart, cnt, csr_sw,
                                             dinv, bias, Wnext, hout);
    }
    const u16* hn = bufB;   // layer 8 output

    pool_kernel<<<N_GRAPH * 16, 256, 0, stream>>>(hn, poolbuf);
    poolwp_kernel<<<N_GRAPH, C_H, 0, stream>>>(poolbuf, Wp, poolwp);
    final_kernel<<<N_NODES / 4, 256, 0, stream>>>(hn, poolwp, Wa, out, N_NODES);
}